// Round 12
// baseline (231.638 us; speedup 1.0000x reference)
//
#include <hip/hip_runtime.h>

#define NN 1024
#define FF 64
#define CC 4
#define EE 32768
#define HH 256

// ---- workspace layout (units of 4-byte words) ----
// zeroed region (one small memset): cnt + mask. adense zeroed by k_count.
#define OFF_ADENSE 0u         // 4194304 f  (N*N*C)
#define OFF_CNT    4194304u   // 4096 i
#define OFF_MASK   4198400u   // 32768 u32 (1 bit per (i,j) pair)
// ---- end of zero region: 4231168 words
#define OFF_OFFS   4231168u   // 4097 i
#define OFF_CURSOR 4235268u   // 4096 i
#define OFF_SRTS   4239364u   // 131072 i
#define OFF_SRTW   4370436u   // 131072 f
#define OFF_P      4501508u   // 262144 f
#define OFF_Q      4763652u   // 262144 f
#define OFF_QT     5025796u   // 262144 f  (Q transposed-packed: QTP[hq][j] float4)
// end 5287940 words = 21.2 MB

// ---------------------------------------------------------------------------
// S1: bucket counts per (c, dst) + zero adense (lane-consecutive full-line
// float4 stores, verified safe rounds 0-10).
__global__ __launch_bounds__(256)
void k_count(const int* __restrict__ ei, int* __restrict__ cnt,
             float4* __restrict__ adense4)
{
    unsigned t = blockIdx.x * 256u + threadIdx.x;   // t < C*E = 131072
    unsigned e = t & (EE - 1u);
    unsigned c = t >> 15;
    int dst = ei[c * 2 * EE + EE + e];
    atomicAdd(&cnt[c * NN + dst], 1);

    const unsigned base = blockIdx.x * 2048u + threadIdx.x;
    const float4 z = make_float4(0.f, 0.f, 0.f, 0.f);
#pragma unroll
    for (int u = 0; u < 8; ++u)
        adense4[base + u * 256u] = z;
}

// S2: exclusive prefix sum over 4096 counts.
__global__ __launch_bounds__(256)
void k_scan(const int* __restrict__ cnt, int* __restrict__ offs, int* __restrict__ cursor)
{
    __shared__ int wsum[4];
    const int t = threadIdx.x;
    int c[16];
    int s = 0;
    const int4* cp = (const int4*)(cnt + t * 16);
#pragma unroll
    for (int u = 0; u < 4; ++u) {
        int4 v = cp[u];
        c[u * 4 + 0] = v.x; c[u * 4 + 1] = v.y; c[u * 4 + 2] = v.z; c[u * 4 + 3] = v.w;
        s += v.x + v.y + v.z + v.w;
    }
    int incl = s;
#pragma unroll
    for (int d = 1; d < 64; d <<= 1) {
        int v = __shfl_up(incl, d, 64);
        if ((t & 63) >= d) incl += v;
    }
    const int w = t >> 6;
    if ((t & 63) == 63) wsum[w] = incl;
    __syncthreads();
    int base = incl - s;                    // exclusive within wave
    for (int ww = 0; ww < w; ++ww) base += wsum[ww];
    int run = base;
#pragma unroll
    for (int u = 0; u < 16; ++u) {
        offs[t * 16 + u] = run;
        cursor[t * 16 + u] = run;
        run += c[u];
    }
    if (t == 255) offs[4096] = run;
}

// S3: bucket-scatter edges + dense adjacency atomics + 1-bit pair mask.
__global__ __launch_bounds__(256)
void k_bucket_adj(const int* __restrict__ ei, const float* __restrict__ ew,
                  int* __restrict__ cursor, int* __restrict__ srt_src,
                  float* __restrict__ srt_w, float* __restrict__ adense,
                  unsigned* __restrict__ mask)
{
    unsigned t = blockIdx.x * 256u + threadIdx.x;
    unsigned e = t & (EE - 1u);
    unsigned c = t >> 15;
    int src = ei[c * 2 * EE + e];
    int dst = ei[c * 2 * EE + EE + e];
    float w = ew[c * EE + e];
    int pos = atomicAdd(&cursor[c * NN + dst], 1);
    srt_src[pos] = src;
    srt_w[pos] = w;
    unsigned pair = (unsigned)src * NN + (unsigned)dst;
    atomicAdd(&adense[(size_t)pair * CC + c], w);
    atomicOr(&mask[pair >> 5], 1u << (pair & 31u));
}

// ---------------------------------------------------------------------------
// Fused node pipeline (unchanged, verified).
__global__ __launch_bounds__(1024)
void k_node(const float* __restrict__ x, const int* __restrict__ offs,
            const int* __restrict__ srt_src, const float* __restrict__ srt_w,
            const float* __restrict__ Wn1, const float* __restrict__ bn1,
            const float* __restrict__ Wn2, const float* __restrict__ bn2,
            const float* __restrict__ We1, const float* __restrict__ be1,
            const float* __restrict__ epsp,
            float* __restrict__ P, float* __restrict__ Q)
{
    __shared__ float hval[4][256];
    __shared__ float hidl[4][256];
    __shared__ float part[4][4][64];
    __shared__ float xnl[4][64];
    const int tid = threadIdx.x;
    const int n0 = blockIdx.x * 4;

    {
        const int w = tid >> 6, lane = tid & 63;
        const int c = w & 3, nn = w >> 2;
        const int g = c * NN + (n0 + nn);
        const int beg = offs[g], end = offs[g + 1];
        float acc = 0.f;
        for (int k = beg; k < end; ++k)
            acc += x[srt_src[k] * FF + lane] * srt_w[k];
        const float ope = 1.0f + epsp[0];
        hval[nn][c * 64 + lane] = acc + ope * x[(n0 + nn) * FF + lane];
    }
    __syncthreads();

    {
        const int nn = tid >> 8, h = tid & 255;
        float acc = bn1[h];
#pragma unroll 8
        for (int k = 0; k < 256; ++k)
            acc += hval[nn][k] * Wn1[k * 256 + h];
        hidl[nn][h] = fmaxf(acc, 0.f);
    }
    __syncthreads();

    {
        const int kq = tid >> 8, nn = (tid >> 6) & 3, f = tid & 63;
        float p = 0.f;
#pragma unroll 8
        for (int k = kq * 64; k < kq * 64 + 64; ++k)
            p += hidl[nn][k] * Wn2[k * 64 + f];
        part[kq][nn][f] = p;
    }
    __syncthreads();
    if (tid < 256) {
        const int nn = tid >> 6, f = tid & 63;
        xnl[nn][f] = bn2[f] + part[0][nn][f] + part[1][nn][f]
                             + part[2][nn][f] + part[3][nn][f];
    }
    __syncthreads();

    {
        const int r = tid >> 8, h = tid & 255;
        float p = be1[h], q = 0.f;
#pragma unroll 8
        for (int f = 0; f < 64; ++f) {
            float xv = xnl[r][f];
            p += xv * We1[(4 + f) * 256 + h];
            q += xv * We1[(68 + f) * 256 + h];
        }
        P[(n0 + r) * 256 + h] = p;
        Q[(n0 + r) * 256 + h] = q;
    }
}

// ---------------------------------------------------------------------------
// Transpose Q[N][256] -> QTP[hq][j] (float4 per (h-quad, node)). LDS-tiled;
// both global read and write are lane-consecutive full-line accesses.
__global__ __launch_bounds__(256)
void k_qt(const float4* __restrict__ Q4, float4* __restrict__ QTP)
{
    __shared__ float4 qt[32 * 64];    // 32 KB
    const int t = threadIdx.x;
    const int n0 = blockIdx.x * 32;
#pragma unroll
    for (int u = 0; u < 8; ++u) {
        int idx = t + u * 256;
        int row = idx >> 6, quad = idx & 63;
        qt[row * 64 + (quad ^ (row & 7))] = Q4[(n0 + row) * 64 + quad];
    }
    __syncthreads();
#pragma unroll
    for (int u = 0; u < 8; ++u) {
        int idx = t + u * 256;
        int hq = idx >> 5, jl = idx & 31;
        QTP[hq * NN + n0 + jl] = qt[jl * 64 + (hq ^ (jl & 7))];
    }
}

// ---------------------------------------------------------------------------
// Edge MLP, LDS-free dense loop. Block = 4 waves; wave w owns i-row iBase+w,
// lane owns j = jBase+lane (tile 4i x 64j, grid 256x16 = 4096 blocks).
// Round-10 pipe analysis: old 32x32 LDS-staged loop put the LDS pipe at 100%
// (4 ds_read_b128 x 12cyc = 48 LDS-cyc vs 192 VALU-cyc per wave-quad, x4
// SIMDs sharing one LDS unit) -> VALUBusy capped ~54%. Here P is read via the
// SCALAR pipe (wave-uniform row, readfirstlane), Q via one coalesced VMEM
// b128 from the transposed QTP, We2 scalar: 24 VALU + 1 VMEM per wave-quad,
// no LDS in the dense loop. Sparse split & fix phase (verified r7-r10)
// unchanged in structure; stores are 1KB contiguous per wave (full lines).
__global__ __launch_bounds__(256, 8)
void k_edge_mlp(const float* __restrict__ P, const float* __restrict__ Q,
                const float4* __restrict__ QTP, const float* __restrict__ adense,
                const unsigned* __restrict__ mask, const float* __restrict__ We1,
                const float* __restrict__ We2, const float* __restrict__ be2,
                float* __restrict__ out)
{
    __shared__ float4 delta[256];   // 4 KB fix-phase results
    __shared__ int nzlist[256];     // 1 KB
    __shared__ int lcnt;

    const int tid = threadIdx.x;
    const int w = tid >> 6, lane = tid & 63;
    const int iBase = blockIdx.y * 4, jBase = blockIdx.x * 64;
    const int i = __builtin_amdgcn_readfirstlane(iBase + w);  // wave-uniform
    const int j = jBase + lane;

    if (tid == 0) lcnt = 0;
    __syncthreads();

    // nonzero detection from 1-bit mask (scalar-friendly: word uniform per
    // 32-lane half). jBase%64==0 so word index = i*32 + (j>>5).
    const unsigned mw = mask[(unsigned)i * 32u + ((unsigned)j >> 5)];
    const bool nz = (mw >> (j & 31)) & 1u;
    if (nz) { int idx = atomicAdd(&lcnt, 1); nzlist[idx] = tid; }

    // dense pass: acc[o] = sum_hq sum_k relu(P[i][hq*4+k]+Q[j][hq*4+k]) * We2[..][o]
    const float4* P4  = (const float4*)P;    // P4[i*64 + hq]
    const float4* W24 = (const float4*)We2;  // W24[h] = We2[h][0..3]
    float ax = 0.f, ay = 0.f, az = 0.f, aw = 0.f;
    for (int hq = 0; hq < 64; ++hq) {
        const float4 qv  = QTP[hq * NN + j];        // coalesced VMEM b128
        const float4 pv  = P4[(size_t)i * 64 + hq]; // scalar pipe
        const float4 w20 = W24[hq * 4 + 0];
        const float4 w21 = W24[hq * 4 + 1];
        const float4 w22 = W24[hq * 4 + 2];
        const float4 w23 = W24[hq * 4 + 3];
        const float v0 = fmaxf(pv.x + qv.x, 0.f);
        const float v1 = fmaxf(pv.y + qv.y, 0.f);
        const float v2 = fmaxf(pv.z + qv.z, 0.f);
        const float v3 = fmaxf(pv.w + qv.w, 0.f);
        ax += v0 * w20.x + v1 * w21.x + v2 * w22.x + v3 * w23.x;
        ay += v0 * w20.y + v1 * w21.y + v2 * w22.y + v3 * w23.y;
        az += v0 * w20.z + v1 * w21.z + v2 * w22.z + v3 * w23.z;
        aw += v0 * w20.w + v1 * w21.w + v2 * w22.w + v3 * w23.w;
    }

    // fix phase (structure verified r7-r10): wave per listed pair, lane over
    // h = u*64+lane, shfl tree-reduce, result to LDS delta.
    __syncthreads();   // all appends done
    {
        const int nfix = lcnt;
        for (int pi = w; pi < nfix; pi += 4) {
            const int lij = nzlist[pi];
            const int gi = iBase + (lij >> 6), gj = jBase + (lij & 63);
            const float4 a = *(const float4*)(adense + ((size_t)gi * NN + gj) * 4);
            float o0 = 0.f, o1 = 0.f, o2 = 0.f, o3 = 0.f;
#pragma unroll
            for (int u = 0; u < 4; ++u) {
                const int h = u * 64 + lane;
                float s = a.x * We1[0 * 256 + h] + a.y * We1[1 * 256 + h]
                        + a.z * We1[2 * 256 + h] + a.w * We1[3 * 256 + h];
                float v = fmaxf(P[gi * 256 + h] + Q[gj * 256 + h] + s, 0.f);
                const float4 w2 = W24[h];
                o0 += v * w2.x; o1 += v * w2.y; o2 += v * w2.z; o3 += v * w2.w;
            }
#pragma unroll
            for (int d = 32; d > 0; d >>= 1) {
                o0 += __shfl_down(o0, d, 64);
                o1 += __shfl_down(o1, d, 64);
                o2 += __shfl_down(o2, d, 64);
                o3 += __shfl_down(o3, d, 64);
            }
            if (lane == 0)
                delta[lij] = make_float4(o0, o1, o2, o3);
        }
    }
    __syncthreads();

    // merge + store: one float4 per pair, lane-consecutive -> 1KB contiguous
    // per wave (full 128B lines by construction).
    const float4 b2 = *(const float4*)be2;
    const float4 dfx = delta[tid];
    float4 o;
    o.x = (nz ? dfx.x : ax) + b2.x;
    o.y = (nz ? dfx.y : ay) + b2.y;
    o.z = (nz ? dfx.z : az) + b2.z;
    o.w = (nz ? dfx.w : aw) + b2.w;
    *(float4*)(out + ((size_t)i * NN + j) * 4) = o;
}

// ---------------------------------------------------------------------------
extern "C" void kernel_launch(void* const* d_in, const int* in_sizes, int n_in,
                              void* d_out, int out_size, void* d_ws, size_t ws_size,
                              hipStream_t stream)
{
    (void)in_sizes; (void)n_in; (void)out_size; (void)ws_size;
    const float* x   = (const float*)d_in[0];
    const int*   ei  = (const int*)d_in[1];
    const float* ew  = (const float*)d_in[2];
    const float* Wn1 = (const float*)d_in[3];
    const float* bn1 = (const float*)d_in[4];
    const float* Wn2 = (const float*)d_in[5];
    const float* bn2 = (const float*)d_in[6];
    const float* We1 = (const float*)d_in[7];
    const float* be1 = (const float*)d_in[8];
    const float* We2 = (const float*)d_in[9];
    const float* be2 = (const float*)d_in[10];
    const float* eps = (const float*)d_in[11];
    float* out = (float*)d_out;

    float*    ws     = (float*)d_ws;
    float*    adense = ws + OFF_ADENSE;
    int*      cnt    = (int*)(ws + OFF_CNT);
    unsigned* mask   = (unsigned*)(ws + OFF_MASK);
    int*      offs   = (int*)(ws + OFF_OFFS);
    int*      cursor = (int*)(ws + OFF_CURSOR);
    int*      srts   = (int*)(ws + OFF_SRTS);
    float*    srtw   = ws + OFF_SRTW;
    float*    Pb     = ws + OFF_P;
    float*    Qb     = ws + OFF_Q;
    float*    QTb    = ws + OFF_QT;

    // zero cnt + mask only (adense zeroed inside k_count)
    (void)hipMemsetAsync((void*)cnt, 0, (size_t)(4096 + 32768) * sizeof(int), stream);

    k_count     <<<(CC * EE) / 256, 256, 0, stream>>>(ei, cnt, (float4*)adense);
    k_scan      <<<1, 256, 0, stream>>>(cnt, offs, cursor);
    k_bucket_adj<<<(CC * EE) / 256, 256, 0, stream>>>(ei, ew, cursor, srts, srtw,
                                                      adense, mask);
    k_node      <<<NN / 4, 1024, 0, stream>>>(x, offs, srts, srtw,
                                              Wn1, bn1, Wn2, bn2, We1, be1, eps, Pb, Qb);
    k_qt        <<<NN / 32, 256, 0, stream>>>((const float4*)Qb, (float4*)QTb);

    dim3 g(NN / 64, NN / 4);
    k_edge_mlp<<<g, 256, 0, stream>>>(Pb, Qb, (const float4*)QTb, adense, mask,
                                      We1, We2, be2, out);
}

// Round 13
// 225.006 us; speedup vs baseline: 1.0295x; 1.0295x over previous
//
#include <hip/hip_runtime.h>

#define NN 1024
#define FF 64
#define CC 4
#define EE 32768
#define HH 256

// ---- workspace layout (units of 4-byte words) ----
// zeroed region (one small memset): cnt + mask. adense zeroed by k_count.
#define OFF_ADENSE 0u         // 4194304 f  (N*N*C)
#define OFF_CNT    4194304u   // 4096 i
#define OFF_MASK   4198400u   // 32768 u32 (1 bit per (i,j) pair)
// ---- end of zero region: 4231168 words
#define OFF_OFFS   4231168u   // 4097 i
#define OFF_CURSOR 4235268u   // 4096 i
#define OFF_SRTS   4239364u   // 131072 i
#define OFF_SRTW   4370436u   // 131072 f
#define OFF_P      4501508u   // 262144 f
#define OFF_Q      4763652u   // 262144 f
#define OFF_QT     5025796u   // 262144 f  (Q transposed-packed: QTP[hq][j] float4)
// end 5287940 words = 21.2 MB

// ---------------------------------------------------------------------------
// S1: bucket counts per (c, dst) + zero adense (lane-consecutive full-line
// float4 stores, verified safe rounds 0-12).
__global__ __launch_bounds__(256)
void k_count(const int* __restrict__ ei, int* __restrict__ cnt,
             float4* __restrict__ adense4)
{
    unsigned t = blockIdx.x * 256u + threadIdx.x;   // t < C*E = 131072
    unsigned e = t & (EE - 1u);
    unsigned c = t >> 15;
    int dst = ei[c * 2 * EE + EE + e];
    atomicAdd(&cnt[c * NN + dst], 1);

    const unsigned base = blockIdx.x * 2048u + threadIdx.x;
    const float4 z = make_float4(0.f, 0.f, 0.f, 0.f);
#pragma unroll
    for (int u = 0; u < 8; ++u)
        adense4[base + u * 256u] = z;
}

// S2: exclusive prefix sum over 4096 counts.
__global__ __launch_bounds__(256)
void k_scan(const int* __restrict__ cnt, int* __restrict__ offs, int* __restrict__ cursor)
{
    __shared__ int wsum[4];
    const int t = threadIdx.x;
    int c[16];
    int s = 0;
    const int4* cp = (const int4*)(cnt + t * 16);
#pragma unroll
    for (int u = 0; u < 4; ++u) {
        int4 v = cp[u];
        c[u * 4 + 0] = v.x; c[u * 4 + 1] = v.y; c[u * 4 + 2] = v.z; c[u * 4 + 3] = v.w;
        s += v.x + v.y + v.z + v.w;
    }
    int incl = s;
#pragma unroll
    for (int d = 1; d < 64; d <<= 1) {
        int v = __shfl_up(incl, d, 64);
        if ((t & 63) >= d) incl += v;
    }
    const int w = t >> 6;
    if ((t & 63) == 63) wsum[w] = incl;
    __syncthreads();
    int base = incl - s;                    // exclusive within wave
    for (int ww = 0; ww < w; ++ww) base += wsum[ww];
    int run = base;
#pragma unroll
    for (int u = 0; u < 16; ++u) {
        offs[t * 16 + u] = run;
        cursor[t * 16 + u] = run;
        run += c[u];
    }
    if (t == 255) offs[4096] = run;
}

// S3: bucket-scatter edges + dense adjacency atomics + 1-bit pair mask.
__global__ __launch_bounds__(256)
void k_bucket_adj(const int* __restrict__ ei, const float* __restrict__ ew,
                  int* __restrict__ cursor, int* __restrict__ srt_src,
                  float* __restrict__ srt_w, float* __restrict__ adense,
                  unsigned* __restrict__ mask)
{
    unsigned t = blockIdx.x * 256u + threadIdx.x;
    unsigned e = t & (EE - 1u);
    unsigned c = t >> 15;
    int src = ei[c * 2 * EE + e];
    int dst = ei[c * 2 * EE + EE + e];
    float w = ew[c * EE + e];
    int pos = atomicAdd(&cursor[c * NN + dst], 1);
    srt_src[pos] = src;
    srt_w[pos] = w;
    unsigned pair = (unsigned)src * NN + (unsigned)dst;
    atomicAdd(&adense[(size_t)pair * CC + c], w);
    atomicOr(&mask[pair >> 5], 1u << (pair & 31u));
}

// ---------------------------------------------------------------------------
// Fused node pipeline (unchanged, verified).
__global__ __launch_bounds__(1024)
void k_node(const float* __restrict__ x, const int* __restrict__ offs,
            const int* __restrict__ srt_src, const float* __restrict__ srt_w,
            const float* __restrict__ Wn1, const float* __restrict__ bn1,
            const float* __restrict__ Wn2, const float* __restrict__ bn2,
            const float* __restrict__ We1, const float* __restrict__ be1,
            const float* __restrict__ epsp,
            float* __restrict__ P, float* __restrict__ Q)
{
    __shared__ float hval[4][256];
    __shared__ float hidl[4][256];
    __shared__ float part[4][4][64];
    __shared__ float xnl[4][64];
    const int tid = threadIdx.x;
    const int n0 = blockIdx.x * 4;

    {
        const int w = tid >> 6, lane = tid & 63;
        const int c = w & 3, nn = w >> 2;
        const int g = c * NN + (n0 + nn);
        const int beg = offs[g], end = offs[g + 1];
        float acc = 0.f;
        for (int k = beg; k < end; ++k)
            acc += x[srt_src[k] * FF + lane] * srt_w[k];
        const float ope = 1.0f + epsp[0];
        hval[nn][c * 64 + lane] = acc + ope * x[(n0 + nn) * FF + lane];
    }
    __syncthreads();

    {
        const int nn = tid >> 8, h = tid & 255;
        float acc = bn1[h];
#pragma unroll 8
        for (int k = 0; k < 256; ++k)
            acc += hval[nn][k] * Wn1[k * 256 + h];
        hidl[nn][h] = fmaxf(acc, 0.f);
    }
    __syncthreads();

    {
        const int kq = tid >> 8, nn = (tid >> 6) & 3, f = tid & 63;
        float p = 0.f;
#pragma unroll 8
        for (int k = kq * 64; k < kq * 64 + 64; ++k)
            p += hidl[nn][k] * Wn2[k * 64 + f];
        part[kq][nn][f] = p;
    }
    __syncthreads();
    if (tid < 256) {
        const int nn = tid >> 6, f = tid & 63;
        xnl[nn][f] = bn2[f] + part[0][nn][f] + part[1][nn][f]
                             + part[2][nn][f] + part[3][nn][f];
    }
    __syncthreads();

    {
        const int r = tid >> 8, h = tid & 255;
        float p = be1[h], q = 0.f;
#pragma unroll 8
        for (int f = 0; f < 64; ++f) {
            float xv = xnl[r][f];
            p += xv * We1[(4 + f) * 256 + h];
            q += xv * We1[(68 + f) * 256 + h];
        }
        P[(n0 + r) * 256 + h] = p;
        Q[(n0 + r) * 256 + h] = q;
    }
}

// ---------------------------------------------------------------------------
// Transpose Q[N][256] -> QTP[hq][j] (float4 per (h-quad, node)). LDS-tiled;
// both global read and write are lane-consecutive full-line accesses.
__global__ __launch_bounds__(256)
void k_qt(const float4* __restrict__ Q4, float4* __restrict__ QTP)
{
    __shared__ float4 qt[32 * 64];    // 32 KB
    const int t = threadIdx.x;
    const int n0 = blockIdx.x * 32;
#pragma unroll
    for (int u = 0; u < 8; ++u) {
        int idx = t + u * 256;
        int row = idx >> 6, quad = idx & 63;
        qt[row * 64 + (quad ^ (row & 7))] = Q4[(n0 + row) * 64 + quad];
    }
    __syncthreads();
#pragma unroll
    for (int u = 0; u < 8; ++u) {
        int idx = t + u * 256;
        int hq = idx >> 5, jl = idx & 31;
        QTP[hq * NN + n0 + jl] = qt[jl * 64 + (hq ^ (jl & 7))];
    }
}

// ---------------------------------------------------------------------------
// Edge MLP, LDS-free dense loop (structure identical to round 12). SINGLE
// change vs r12: __launch_bounds__ 2nd arg 8 -> 4. The (256,8) bound capped
// the allocator at 64 VGPR; compiler landed at 32 VGPR + scratch-spilled the
// inner-loop state (r12 PMC: +28 MB WRITE / +16 MB FETCH ~= 28 B/thread
// spill-fill, VALUBusy pinned at 58%). (256,4) gives a 128-VGPR budget;
// every (256,4) round (r7/r9/r10) had spill-clean traffic.
__global__ __launch_bounds__(256, 4)
void k_edge_mlp(const float* __restrict__ P, const float* __restrict__ Q,
                const float4* __restrict__ QTP, const float* __restrict__ adense,
                const unsigned* __restrict__ mask, const float* __restrict__ We1,
                const float* __restrict__ We2, const float* __restrict__ be2,
                float* __restrict__ out)
{
    __shared__ float4 delta[256];   // 4 KB fix-phase results
    __shared__ int nzlist[256];     // 1 KB
    __shared__ int lcnt;

    const int tid = threadIdx.x;
    const int w = tid >> 6, lane = tid & 63;
    const int iBase = blockIdx.y * 4, jBase = blockIdx.x * 64;
    const int i = __builtin_amdgcn_readfirstlane(iBase + w);  // wave-uniform
    const int j = jBase + lane;

    if (tid == 0) lcnt = 0;
    __syncthreads();

    // nonzero detection from 1-bit mask (broadcast-friendly reads)
    const unsigned mw = mask[(unsigned)i * 32u + ((unsigned)j >> 5)];
    const bool nz = (mw >> (j & 31)) & 1u;
    if (nz) { int idx = atomicAdd(&lcnt, 1); nzlist[idx] = tid; }

    // dense pass: acc[o] = sum_hq sum_k relu(P[i][hq*4+k]+Q[j][hq*4+k]) * We2[..][o]
    const float4* P4  = (const float4*)P;    // P4[i*64 + hq]
    const float4* W24 = (const float4*)We2;  // W24[h] = We2[h][0..3]
    float ax = 0.f, ay = 0.f, az = 0.f, aw = 0.f;
    for (int hq = 0; hq < 64; ++hq) {
        const float4 qv  = QTP[hq * NN + j];        // coalesced VMEM b128
        const float4 pv  = P4[(size_t)i * 64 + hq]; // scalar pipe
        const float4 w20 = W24[hq * 4 + 0];
        const float4 w21 = W24[hq * 4 + 1];
        const float4 w22 = W24[hq * 4 + 2];
        const float4 w23 = W24[hq * 4 + 3];
        const float v0 = fmaxf(pv.x + qv.x, 0.f);
        const float v1 = fmaxf(pv.y + qv.y, 0.f);
        const float v2 = fmaxf(pv.z + qv.z, 0.f);
        const float v3 = fmaxf(pv.w + qv.w, 0.f);
        ax += v0 * w20.x + v1 * w21.x + v2 * w22.x + v3 * w23.x;
        ay += v0 * w20.y + v1 * w21.y + v2 * w22.y + v3 * w23.y;
        az += v0 * w20.z + v1 * w21.z + v2 * w22.z + v3 * w23.z;
        aw += v0 * w20.w + v1 * w21.w + v2 * w22.w + v3 * w23.w;
    }

    // fix phase (structure verified r7-r12): wave per listed pair, lane over
    // h = u*64+lane, shfl tree-reduce, result to LDS delta.
    __syncthreads();   // all appends done
    {
        const int nfix = lcnt;
        for (int pi = w; pi < nfix; pi += 4) {
            const int lij = nzlist[pi];
            const int gi = iBase + (lij >> 6), gj = jBase + (lij & 63);
            const float4 a = *(const float4*)(adense + ((size_t)gi * NN + gj) * 4);
            float o0 = 0.f, o1 = 0.f, o2 = 0.f, o3 = 0.f;
#pragma unroll
            for (int u = 0; u < 4; ++u) {
                const int h = u * 64 + lane;
                float s = a.x * We1[0 * 256 + h] + a.y * We1[1 * 256 + h]
                        + a.z * We1[2 * 256 + h] + a.w * We1[3 * 256 + h];
                float v = fmaxf(P[gi * 256 + h] + Q[gj * 256 + h] + s, 0.f);
                const float4 w2 = W24[h];
                o0 += v * w2.x; o1 += v * w2.y; o2 += v * w2.z; o3 += v * w2.w;
            }
#pragma unroll
            for (int d = 32; d > 0; d >>= 1) {
                o0 += __shfl_down(o0, d, 64);
                o1 += __shfl_down(o1, d, 64);
                o2 += __shfl_down(o2, d, 64);
                o3 += __shfl_down(o3, d, 64);
            }
            if (lane == 0)
                delta[lij] = make_float4(o0, o1, o2, o3);
        }
    }
    __syncthreads();

    // merge + store: one float4 per pair, lane-consecutive -> 1KB contiguous
    // per wave (full 128B lines by construction).
    const float4 b2 = *(const float4*)be2;
    const float4 dfx = delta[tid];
    float4 o;
    o.x = (nz ? dfx.x : ax) + b2.x;
    o.y = (nz ? dfx.y : ay) + b2.y;
    o.z = (nz ? dfx.z : az) + b2.z;
    o.w = (nz ? dfx.w : aw) + b2.w;
    *(float4*)(out + ((size_t)i * NN + j) * 4) = o;
}

// ---------------------------------------------------------------------------
extern "C" void kernel_launch(void* const* d_in, const int* in_sizes, int n_in,
                              void* d_out, int out_size, void* d_ws, size_t ws_size,
                              hipStream_t stream)
{
    (void)in_sizes; (void)n_in; (void)out_size; (void)ws_size;
    const float* x   = (const float*)d_in[0];
    const int*   ei  = (const int*)d_in[1];
    const float* ew  = (const float*)d_in[2];
    const float* Wn1 = (const float*)d_in[3];
    const float* bn1 = (const float*)d_in[4];
    const float* Wn2 = (const float*)d_in[5];
    const float* bn2 = (const float*)d_in[6];
    const float* We1 = (const float*)d_in[7];
    const float* be1 = (const float*)d_in[8];
    const float* We2 = (const float*)d_in[9];
    const float* be2 = (const float*)d_in[10];
    const float* eps = (const float*)d_in[11];
    float* out = (float*)d_out;

    float*    ws     = (float*)d_ws;
    float*    adense = ws + OFF_ADENSE;
    int*      cnt    = (int*)(ws + OFF_CNT);
    unsigned* mask   = (unsigned*)(ws + OFF_MASK);
    int*      offs   = (int*)(ws + OFF_OFFS);
    int*      cursor = (int*)(ws + OFF_CURSOR);
    int*      srts   = (int*)(ws + OFF_SRTS);
    float*    srtw   = ws + OFF_SRTW;
    float*    Pb     = ws + OFF_P;
    float*    Qb     = ws + OFF_Q;
    float*    QTb    = ws + OFF_QT;

    // zero cnt + mask only (adense zeroed inside k_count)
    (void)hipMemsetAsync((void*)cnt, 0, (size_t)(4096 + 32768) * sizeof(int), stream);

    k_count     <<<(CC * EE) / 256, 256, 0, stream>>>(ei, cnt, (float4*)adense);
    k_scan      <<<1, 256, 0, stream>>>(cnt, offs, cursor);
    k_bucket_adj<<<(CC * EE) / 256, 256, 0, stream>>>(ei, ew, cursor, srts, srtw,
                                                      adense, mask);
    k_node      <<<NN / 4, 1024, 0, stream>>>(x, offs, srts, srtw,
                                              Wn1, bn1, Wn2, bn2, We1, be1, eps, Pb, Qb);
    k_qt        <<<NN / 32, 256, 0, stream>>>((const float4*)Qb, (float4*)QTb);

    dim3 g(NN / 64, NN / 4);
    k_edge_mlp<<<g, 256, 0, stream>>>(Pb, Qb, (const float4*)QTb, adense, mask,
                                      We1, We2, be2, out);
}